// Round 1
// baseline (190.715 us; speedup 1.0000x reference)
//
#include <hip/hip_runtime.h>

typedef float f32x4 __attribute__((ext_vector_type(4)));
typedef short bf16x8 __attribute__((ext_vector_type(8)));

#define MFMA16(a, b, c) __builtin_amdgcn_mfma_f32_16x16x32_bf16((a), (b), (c), 0, 0, 0)

#define NN 4096
#define DD 256
#define SCALE 0.0625f

static __device__ __forceinline__ unsigned short f2bf(float f) {
  unsigned int u = __float_as_uint(f);
  u += 0x7FFFu + ((u >> 16) & 1u);   // round-to-nearest-even
  return (unsigned short)(u >> 16);
}

static __device__ __forceinline__ float softplusf(float x) {
  return (x > 20.f) ? x : log1pf(__expf(x));
}

// ---------------------------------------------------------------------------
// Prep: q/k transpose [B,C,N] -> [B,N,C] (+pos), cast to bf16.
// grid (N/32, C/32, B*2); z: b = z&1, which = z>>1 (0=q, 1=k)
// ---------------------------------------------------------------------------
__global__ __launch_bounds__(256) void prep_qk(
    const float* __restrict__ q, const float* __restrict__ k,
    const float* __restrict__ qp, const float* __restrict__ kp,
    unsigned short* __restrict__ qbf, unsigned short* __restrict__ kbf) {
  int n0 = blockIdx.x * 32, c0 = blockIdx.y * 32;
  int b = blockIdx.z & 1, which = blockIdx.z >> 1;
  const float* src = which ? k : q;
  const float* pos = which ? kp : qp;
  unsigned short* dst = which ? kbf : qbf;

  __shared__ float tile[32][33];
  int tx = threadIdx.x & 31, ty = threadIdx.x >> 5;
#pragma unroll
  for (int i = 0; i < 4; ++i) {
    int c = c0 + ty + i * 8;
    tile[ty + i * 8][tx] = src[((size_t)(b * DD + c)) * NN + n0 + tx];
  }
  __syncthreads();
#pragma unroll
  for (int i = 0; i < 4; ++i) {
    int n = n0 + ty + i * 8;
    float v = tile[tx][ty + i * 8] + pos[(size_t)n * DD + c0 + tx];
    dst[((size_t)(b * NN + n)) * DD + c0 + tx] = f2bf(v);
  }
}

// ---------------------------------------------------------------------------
// Prep: v cast (keeps [B,C,N] layout == V^T, what PV's B-fragment wants)
// plus column sum colsum[b*256+c] = sum_n values[b,c,n].  grid 512.
// ---------------------------------------------------------------------------
__global__ __launch_bounds__(256) void prep_v(
    const float* __restrict__ src, unsigned short* __restrict__ vbf,
    float* __restrict__ colsum) {
  int row = blockIdx.x;  // b*256 + c
  const float* s = src + (size_t)row * NN;
  unsigned short* d = vbf + (size_t)row * NN;
  int tid = threadIdx.x;
  float sum = 0.f;
#pragma unroll
  for (int i = 0; i < 16; ++i) {
    int n = tid + i * 256;
    float v = s[n];
    sum += v;
    d[n] = f2bf(v);
  }
#pragma unroll
  for (int off = 1; off < 64; off <<= 1) sum += __shfl_xor(sum, off);
  __shared__ float ps[4];
  if ((tid & 63) == 0) ps[tid >> 6] = sum;
  __syncthreads();
  if (tid == 0) colsum[row] = ps[0] + ps[1] + ps[2] + ps[3];
}

// ---------------------------------------------------------------------------
// Prep: mask_map scalars. nearest 128->64 resize is src[2y][2x]; we need
// sum of squares over the 64x64 grid. grid 4: b = bid>>1, which = bid&1.
// ---------------------------------------------------------------------------
__global__ __launch_bounds__(256) void prep_mask(
    const float* __restrict__ me, const float* __restrict__ mm,
    float* __restrict__ msums) {
  int b = blockIdx.x >> 1, which = blockIdx.x & 1;
  const float* m = which ? mm : me;
  int tid = threadIdx.x;
  float sum = 0.f;
#pragma unroll
  for (int i = 0; i < 16; ++i) {
    int p = tid + i * 256;          // 0..4095 over the 64x64 grid
    int y = p >> 6, x = p & 63;
    float v = m[(size_t)(b * 128 + 2 * y) * 128 + 2 * x];
    sum += v * v;
  }
#pragma unroll
  for (int off = 1; off < 64; off <<= 1) sum += __shfl_xor(sum, off);
  __shared__ float ps[4];
  if ((tid & 63) == 0) ps[tid >> 6] = sum;
  __syncthreads();
  if (tid == 0) msums[blockIdx.x] = ps[0] + ps[1] + ps[2] + ps[3];
}

// ---------------------------------------------------------------------------
// Flash attention. 256 blocks (b, q-tile of 32), 4 waves.
// Wave w: QK^T col-tile w (16 kv rows), PV col range [w*64, w*64+64).
// Both M-tiles (16 q rows each) per wave -> K/V reads partition exactly.
// ---------------------------------------------------------------------------
__global__ __launch_bounds__(256) void attn_kernel(
    const unsigned short* __restrict__ qbf,
    const unsigned short* __restrict__ kbf,
    const unsigned short* __restrict__ vbf,
    const float* __restrict__ colsum,
    const float* __restrict__ msums,
    const float* __restrict__ bias_eye,
    const float* __restrict__ bias_mouth,
    float* __restrict__ out) {
  // XCD-chunked swizzle: hw block h -> xcd h%8 serves 32 consecutive q-tiles
  int h = blockIdx.x;
  int bid = (h & 7) * 32 + (h >> 3);
  int b = bid >> 7;
  int qbase = (bid & 127) * 32;

  int tid = threadIdx.x;
  int wid = tid >> 6;
  int lane = tid & 63;
  int lg = lane >> 4;   // 0..3
  int ll = lane & 15;

  __shared__ float S_lds[32][65];
  __shared__ __align__(16) unsigned short P_lds[32][72];
  __shared__ float m_st[32], l_st[32], sc_st[32];

  if (tid < 32) { m_st[tid] = -1e30f; l_st[tid] = 0.f; }

  // Q fragments held in registers: qf[m][ks], A-layout row=ll, k=lg*8+j
  bf16x8 qf[2][8];
  {
    const unsigned short* qb = qbf + (size_t)(b * NN + qbase) * DD;
#pragma unroll
    for (int m = 0; m < 2; ++m)
#pragma unroll
      for (int ks = 0; ks < 8; ++ks)
        qf[m][ks] = *(const bf16x8*)(qb + (size_t)(m * 16 + ll) * DD + ks * 32 + lg * 8);
  }

  f32x4 o[2][4];
#pragma unroll
  for (int m = 0; m < 2; ++m)
#pragma unroll
    for (int c = 0; c < 4; ++c) o[m][c] = (f32x4){0.f, 0.f, 0.f, 0.f};

  const unsigned short* kb = kbf + (size_t)b * NN * DD;
  const unsigned short* vb = vbf + (size_t)b * DD * NN;

  __syncthreads();  // stats init visible

  for (int kvb = 0; kvb < NN; kvb += 64) {
    // ---- S = Q K^T (this wave: kv rows kvb + wid*16 + ll)
    f32x4 s0 = (f32x4){0.f, 0.f, 0.f, 0.f};
    f32x4 s1 = (f32x4){0.f, 0.f, 0.f, 0.f};
    const unsigned short* krow = kb + (size_t)(kvb + wid * 16 + ll) * DD;
#pragma unroll
    for (int ks = 0; ks < 8; ++ks) {
      bf16x8 kf = *(const bf16x8*)(krow + ks * 32 + lg * 8);
      s0 = MFMA16(qf[0][ks], kf, s0);
      s1 = MFMA16(qf[1][ks], kf, s1);
    }
#pragma unroll
    for (int r = 0; r < 4; ++r) {
      S_lds[lg * 4 + r][wid * 16 + ll] = s0[r] * SCALE;
      S_lds[16 + lg * 4 + r][wid * 16 + ll] = s1[r] * SCALE;
    }
    __syncthreads();

    // ---- online softmax: 8 threads per row
    {
      int row = tid >> 3, idx = tid & 7;
      float v[8];
      float lm = -1e30f;
#pragma unroll
      for (int c = 0; c < 8; ++c) { v[c] = S_lds[row][idx * 8 + c]; lm = fmaxf(lm, v[c]); }
#pragma unroll
      for (int off = 1; off < 8; off <<= 1) lm = fmaxf(lm, __shfl_xor(lm, off, 8));
      float mo = m_st[row];
      float mn = fmaxf(mo, lm);
      float sum = 0.f;
      bf16x8 pv;
#pragma unroll
      for (int c = 0; c < 8; ++c) {
        float p = __expf(v[c] - mn);
        sum += p;
        pv[c] = (short)f2bf(p);
      }
      *(bf16x8*)(&P_lds[row][idx * 8]) = pv;
#pragma unroll
      for (int off = 1; off < 8; off <<= 1) sum += __shfl_xor(sum, off, 8);
      if (idx == 0) {
        float sc = __expf(mo - mn);
        l_st[row] = l_st[row] * sc + sum;
        m_st[row] = mn;
        sc_st[row] = sc;
      }
    }
    __syncthreads();

    // ---- rescale O by exp(m_old - m_new)
#pragma unroll
    for (int m = 0; m < 2; ++m)
#pragma unroll
      for (int r = 0; r < 4; ++r) {
        float sc = sc_st[m * 16 + lg * 4 + r];
#pragma unroll
        for (int c = 0; c < 4; ++c) o[m][c][r] *= sc;
      }

    // ---- O += P V   (this wave: cols wid*64 .. +64)
    bf16x8 pa[2][2];
#pragma unroll
    for (int m = 0; m < 2; ++m)
#pragma unroll
      for (int ks = 0; ks < 2; ++ks)
        pa[m][ks] = *(const bf16x8*)(&P_lds[m * 16 + ll][ks * 32 + lg * 8]);
#pragma unroll
    for (int ct = 0; ct < 4; ++ct) {
      const unsigned short* vrow = vb + (size_t)(wid * 64 + ct * 16 + ll) * NN + kvb;
#pragma unroll
      for (int ks = 0; ks < 2; ++ks) {
        bf16x8 vf = *(const bf16x8*)(vrow + ks * 32 + lg * 8);
        o[0][ct] = MFMA16(pa[0][ks], vf, o[0][ct]);
        o[1][ct] = MFMA16(pa[1][ks], vf, o[1][ct]);
      }
    }
    // no barrier needed here: next iteration's first barrier orders
    // S_lds/P_lds reuse (each wave finishes PV before passing it).
  }

  // epilogue: out[b,c,q] = O/l + softplus-bias * colsum_v
  float sb = softplusf(bias_eye[0] * msums[b * 2 + 0]) +
             softplusf(bias_mouth[0] * msums[b * 2 + 1]);
#pragma unroll
  for (int m = 0; m < 2; ++m)
#pragma unroll
    for (int r = 0; r < 4; ++r) {
      int qrow = m * 16 + lg * 4 + r;
      float invl = 1.f / l_st[qrow];
      size_t qg = qbase + qrow;
#pragma unroll
      for (int ct = 0; ct < 4; ++ct) {
        int c = wid * 64 + ct * 16 + ll;
        out[((size_t)b * DD + c) * NN + qg] = o[m][ct][r] * invl + sb * colsum[b * DD + c];
      }
    }
}

// ---------------------------------------------------------------------------
extern "C" void kernel_launch(void* const* d_in, const int* in_sizes, int n_in,
                              void* d_out, int out_size, void* d_ws, size_t ws_size,
                              hipStream_t stream) {
  const float* queries    = (const float*)d_in[0];
  const float* keys       = (const float*)d_in[1];
  const float* values     = (const float*)d_in[2];
  const float* mask_eye   = (const float*)d_in[3];
  const float* mask_mouth = (const float*)d_in[4];
  const float* q_pos      = (const float*)d_in[5];
  const float* k_pos      = (const float*)d_in[6];
  const float* bias_eye   = (const float*)d_in[7];
  const float* bias_mouth = (const float*)d_in[8];
  float* out = (float*)d_out;

  char* w = (char*)d_ws;
  unsigned short* qbf = (unsigned short*)(w);                    // 4 MB
  unsigned short* kbf = (unsigned short*)(w + (4u << 20));       // 4 MB
  unsigned short* vbf = (unsigned short*)(w + (8u << 20));       // 4 MB
  float* colsum = (float*)(w + (12u << 20));                     // 2 KB
  float* msums  = (float*)(w + (12u << 20) + 4096);              // 16 B

  prep_qk<<<dim3(128, 8, 4), 256, 0, stream>>>(queries, keys, q_pos, k_pos, qbf, kbf);
  prep_v<<<512, 256, 0, stream>>>(values, vbf, colsum);
  prep_mask<<<4, 256, 0, stream>>>(mask_eye, mask_mouth, msums);
  attn_kernel<<<256, 256, 0, stream>>>(qbf, kbf, vbf, colsum, msums,
                                       bias_eye, bias_mouth, out);
}